// Round 13
// baseline (9485.439 us; speedup 1.0000x reference)
//
#include <hip/hip_runtime.h>

// Problem sizes (fixed by the reference)
constexpr int B = 128, S = 1024, E = 256, H = 512, V = 128;
constexpr int NGROUP = 4, WPG = 13, NWG = 64;   // 4 groups x 16 slots (13 live)
constexpr int GB = B / NGROUP;                  // 32 batch rows per group
constexpr int NT = 512;                         // 8 waves per WG
constexpr unsigned LDS_BYTES = 98304;           // AH/AL 64KB + EH/EL 32KB

using short8 = __attribute__((ext_vector_type(8))) short;
using f32x4  = __attribute__((ext_vector_type(4))) float;
using u16    = unsigned short;

#define MFMA_B16(a, b, c) __builtin_amdgcn_mfma_f32_16x16x32_bf16((a), (b), (c), 0, 0, 0)

// ---- bf16 hi/lo split helpers (v = hi + lo, ~2^-16 rel error) ---------------
__device__ __forceinline__ unsigned pk(float a, float b) {
  return (__builtin_bit_cast(unsigned, b) & 0xFFFF0000u) |
         (__builtin_bit_cast(unsigned, a) >> 16);
}
__device__ __forceinline__ float hif(float a) {
  return __builtin_bit_cast(float, __builtin_bit_cast(unsigned, a) & 0xFFFF0000u);
}
__device__ __forceinline__ void cvt16(const float4& v0, const float4& v1,
                                      const float4& v2, const float4& v3,
                                      uint4& h0, uint4& h1, uint4& l0, uint4& l1) {
  h0 = make_uint4(pk(v0.x, v0.y), pk(v0.z, v0.w), pk(v1.x, v1.y), pk(v1.z, v1.w));
  h1 = make_uint4(pk(v2.x, v2.y), pk(v2.z, v2.w), pk(v3.x, v3.y), pk(v3.z, v3.w));
  l0 = make_uint4(pk(v0.x - hif(v0.x), v0.y - hif(v0.y)),
                  pk(v0.z - hif(v0.z), v0.w - hif(v0.w)),
                  pk(v1.x - hif(v1.x), v1.y - hif(v1.y)),
                  pk(v1.z - hif(v1.z), v1.w - hif(v1.w)));
  l1 = make_uint4(pk(v2.x - hif(v2.x), v2.y - hif(v2.y)),
                  pk(v2.z - hif(v2.z), v2.w - hif(v2.w)),
                  pk(v3.x - hif(v3.x), v3.y - hif(v3.y)),
                  pk(v3.z - hif(v3.z), v3.w - hif(v3.w)));
}

// fast tanh via hardware exp (round-8/12 proven: same absmax as tanhf)
__device__ __forceinline__ float ftanh(float x) {
  float e = __expf(2.0f * x);
  return 1.0f - 2.0f * __builtin_amdgcn_rcpf(e + 1.0f);
}

// ---- system-scope (cross-XCD, fence-free) memory helpers --------------------
__device__ __forceinline__ void stg_sys_f32(float* p, float v) {
  asm volatile("global_store_dword %0, %1, off sc0 sc1" :: "v"(p), "v"(v) : "memory");
}
__device__ __forceinline__ void stg_sys_u32(unsigned* p, unsigned v) {
  asm volatile("global_store_dword %0, %1, off sc0 sc1" :: "v"(p), "v"(v) : "memory");
}
__device__ __forceinline__ void stg_sys_u16(u16* p, unsigned v) {
  asm volatile("global_store_short %0, %1, off sc0 sc1" :: "v"(p), "v"(v) : "memory");
}

// Group barrier (round-7/12 proven primitive): per-WG flag slot, no RMW, no
// cache-maintenance fences. vmcnt(0) drains own sc stores; tid0 publishes;
// wave0 lanes poll the 13 slots with s_sleep backoff.
__device__ __forceinline__ void gbar(unsigned* slots, int r, unsigned target, int tid) {
  asm volatile("s_waitcnt vmcnt(0)" ::: "memory");
  __syncthreads();
  if (tid < 64) {
    if (tid == 0)
      asm volatile("global_store_dword %0, %1, off sc0 sc1"
                   :: "v"(slots + r), "v"(target) : "memory");
    for (;;) {
      unsigned v = target;
      if (tid < WPG)
        asm volatile("global_load_dword %0, %1, off sc0 sc1\n\ts_waitcnt vmcnt(0)"
                     : "=v"(v) : "v"(slots + tid) : "memory");
      if (__all((int)(v >= target))) break;
      __builtin_amdgcn_s_sleep(1);
    }
  }
  __syncthreads();
}

// ---- W fragment -> registers (loaded once): lane (lc=col0+(lane&15),
// q=lane>>4) holds W[lc][ks*32 + q*8 .. +8] as bf16 hi/lo short8 per ks. ------
template <int KK>
__device__ __forceinline__ void loadWfrag(const float* W, int col0, int lane,
                                          short8* wh, short8* wl) {
  const int lc = col0 + (lane & 15);
  const int q = lane >> 4;
#pragma unroll
  for (int ks = 0; ks < KK / 32; ++ks) {
    const float* src = W + (size_t)lc * KK + ks * 32 + q * 8;
    float4 a = *(const float4*)src;
    float4 b = *(const float4*)(src + 4);
    uint4 h = make_uint4(pk(a.x, a.y), pk(a.z, a.w), pk(b.x, b.y), pk(b.z, b.w));
    uint4 l = make_uint4(pk(a.x - hif(a.x), a.y - hif(a.y)),
                         pk(a.z - hif(a.z), a.w - hif(a.w)),
                         pk(b.x - hif(b.x), b.y - hif(b.y)),
                         pk(b.z - hif(b.z), b.w - hif(b.w)));
    wh[ks] = __builtin_bit_cast(short8, h);
    wl[ks] = __builtin_bit_cast(short8, l);
  }
}

// ---- A staging: bf16 hi/lo state planes ([32][512] u16, 32KB each) -> LDS ---
// 512 threads x 4 chunks x 16B per plane.
__device__ __forceinline__ void stage16(int tid, const u16* Ph, const u16* Pl,
                                        char* AH, char* AL) {
  int off[4], lof[4];
#pragma unroll
  for (int it = 0; it < 4; ++it) {
    int s = tid + it * NT, rr = s >> 6, ks = s & 63;
    off[it] = rr * 1024 + ks * 16;
    lof[it] = off[it] ^ ((rr & 7) << 4);
  }
  const char* gh = (const char*)Ph;
  const char* gl = (const char*)Pl;
  float4 a0, a1, a2, a3, b0, b1, b2, b3;
  asm volatile(
      "global_load_dwordx4 %0, %8, off sc0 sc1\n\t"
      "global_load_dwordx4 %1, %9, off sc0 sc1\n\t"
      "global_load_dwordx4 %2, %10, off sc0 sc1\n\t"
      "global_load_dwordx4 %3, %11, off sc0 sc1\n\t"
      "global_load_dwordx4 %4, %12, off sc0 sc1\n\t"
      "global_load_dwordx4 %5, %13, off sc0 sc1\n\t"
      "global_load_dwordx4 %6, %14, off sc0 sc1\n\t"
      "global_load_dwordx4 %7, %15, off sc0 sc1\n\t"
      "s_waitcnt vmcnt(0)"
      : "=&v"(a0), "=&v"(a1), "=&v"(a2), "=&v"(a3),
        "=&v"(b0), "=&v"(b1), "=&v"(b2), "=&v"(b3)
      : "v"(gh + off[0]), "v"(gh + off[1]), "v"(gh + off[2]), "v"(gh + off[3]),
        "v"(gl + off[0]), "v"(gl + off[1]), "v"(gl + off[2]), "v"(gl + off[3])
      : "memory");
  *(float4*)(AH + lof[0]) = a0; *(float4*)(AH + lof[1]) = a1;
  *(float4*)(AH + lof[2]) = a2; *(float4*)(AH + lof[3]) = a3;
  *(float4*)(AL + lof[0]) = b0; *(float4*)(AL + lof[1]) = b1;
  *(float4*)(AL + lof[2]) = b2; *(float4*)(AL + lof[3]) = b3;
}

// Same + 8 fp32 init scalars (rows {r0..r0+3, r0+16..r0+19} via 4 bases with
// offset:0/2048), single vmcnt(0) for all 16 loads.
__device__ __forceinline__ void stage16i(int tid, const u16* Ph, const u16* Pl,
                                         char* AH, char* AL,
                                         const float* q0, const float* q2,
                                         const float* q16, const float* q18,
                                         float* iw) {
  int off[4], lof[4];
#pragma unroll
  for (int it = 0; it < 4; ++it) {
    int s = tid + it * NT, rr = s >> 6, ks = s & 63;
    off[it] = rr * 1024 + ks * 16;
    lof[it] = off[it] ^ ((rr & 7) << 4);
  }
  const char* gh = (const char*)Ph;
  const char* gl = (const char*)Pl;
  float4 a0, a1, a2, a3, b0, b1, b2, b3;
  asm volatile(
      "global_load_dword %8, %20, off sc0 sc1\n\t"
      "global_load_dword %9, %20, off offset:2048 sc0 sc1\n\t"
      "global_load_dword %10, %21, off sc0 sc1\n\t"
      "global_load_dword %11, %21, off offset:2048 sc0 sc1\n\t"
      "global_load_dword %12, %22, off sc0 sc1\n\t"
      "global_load_dword %13, %22, off offset:2048 sc0 sc1\n\t"
      "global_load_dword %14, %23, off sc0 sc1\n\t"
      "global_load_dword %15, %23, off offset:2048 sc0 sc1\n\t"
      "global_load_dwordx4 %0, %16, off sc0 sc1\n\t"
      "global_load_dwordx4 %1, %17, off sc0 sc1\n\t"
      "global_load_dwordx4 %2, %18, off sc0 sc1\n\t"
      "global_load_dwordx4 %3, %19, off sc0 sc1\n\t"
      "global_load_dwordx4 %4, %24, off sc0 sc1\n\t"
      "global_load_dwordx4 %5, %25, off sc0 sc1\n\t"
      "global_load_dwordx4 %6, %26, off sc0 sc1\n\t"
      "global_load_dwordx4 %7, %27, off sc0 sc1\n\t"
      "s_waitcnt vmcnt(0)"
      : "=&v"(a0), "=&v"(a1), "=&v"(a2), "=&v"(a3),
        "=&v"(b0), "=&v"(b1), "=&v"(b2), "=&v"(b3),
        "=&v"(iw[0]), "=&v"(iw[1]), "=&v"(iw[2]), "=&v"(iw[3]),
        "=&v"(iw[4]), "=&v"(iw[5]), "=&v"(iw[6]), "=&v"(iw[7])
      : "v"(gh + off[0]), "v"(gh + off[1]), "v"(gh + off[2]), "v"(gh + off[3]),
        "v"(q0), "v"(q2), "v"(q16), "v"(q18),
        "v"(gl + off[0]), "v"(gl + off[1]), "v"(gl + off[2]), "v"(gl + off[3])
      : "memory");
  *(float4*)(AH + lof[0]) = a0; *(float4*)(AH + lof[1]) = a1;
  *(float4*)(AH + lof[2]) = a2; *(float4*)(AH + lof[3]) = a3;
  *(float4*)(AL + lof[0]) = b0; *(float4*)(AL + lof[1]) = b1;
  *(float4*)(AL + lof[2]) = b2; *(float4*)(AL + lof[3]) = b3;
}

// ---- bf16x3 MFMA, 2 row-tiles (rows rr, rr+16), accumulating ----------------
template <int KK>
__device__ __forceinline__ void mm2(const char* AH, const char* AL,
                                    const short8* wh, const short8* wl,
                                    int lane, f32x4& s0h, f32x4& s0l,
                                    f32x4& s1h, f32x4& s1l) {
  constexpr int ROWB = KK * 2;
  const int rr = lane & 15;
  const int kq = (lane >> 4) * 16;
  const int swa = (rr & 7) << 4;   // same swizzle for rr and rr+16 (16%8==0)
#pragma unroll
  for (int ks = 0; ks < KK / 32; ++ks) {
    int ka0 = rr * ROWB + ks * 64 + kq;
    int ka1 = ka0 + 16 * ROWB;
    short8 ah0 = *(const short8*)(AH + (ka0 ^ swa));
    short8 al0 = *(const short8*)(AL + (ka0 ^ swa));
    short8 ah1 = *(const short8*)(AH + (ka1 ^ swa));
    short8 al1 = *(const short8*)(AL + (ka1 ^ swa));
    s0h = MFMA_B16(ah0, wh[ks], s0h);
    s0l = MFMA_B16(ah0, wl[ks], s0l);
    s0l = MFMA_B16(al0, wh[ks], s0l);
    s1h = MFMA_B16(ah1, wh[ks], s1h);
    s1l = MFMA_B16(ah1, wl[ks], s1l);
    s1l = MFMA_B16(al1, wh[ks], s1l);
  }
}

// ---- role loops --------------------------------------------------------------
// h0 (t=p): h0[t] = tanh(emb[x[:,t]]@W_ih0^T + b_ih0+b_hh0 + h0[t-1]@W_hh0^T)
__device__ void run_h0(int tid, int lane, int w, unsigned* slots, int r,
                       u16* hh, u16* hl, const int* x, const float* emb,
                       const float* b1, const float* b2, float* hnb,
                       const float* Whh, const float* Wih, int tn, int gb0,
                       char* AH, char* AL, char* EH, char* EL) {
  short8 whh[16], wlh[16], whi[8], wli[8];
  loadWfrag<512>(Whh, tn * 128 + w * 16, lane, whh, wlh);
  loadWfrag<256>(Wih, tn * 128 + w * 16, lane, whi, wli);
  const int lc15 = lane & 15, r0 = (lane >> 4) * 4;
  const int gcol = tn * 128 + w * 16 + lc15;
  const float bsum = b1[gcol] + b2[gcol];
  const int er = tid >> 4, eq = tid & 15;  // emb gather: row 0..31, chunk 0..15
  // prologue: gather emb for t=0 (read-only inputs; LDS-local)
  {
    int idx = x[(size_t)(gb0 + er) * S + 0];
    const float4* src = (const float4*)(emb + (size_t)idx * E + eq * 16);
    float4 v0 = src[0], v1 = src[1], v2 = src[2], v3 = src[3];
    uint4 h0v, h1v, l0v, l1v;
    cvt16(v0, v1, v2, v3, h0v, h1v, l0v, l1v);
    int bb = er * 512 + eq * 32, sw = (er & 7) << 4;
    *(uint4*)(EH + (bb ^ sw)) = h0v; *(uint4*)(EH + ((bb + 16) ^ sw)) = h1v;
    *(uint4*)(EL + (bb ^ sw)) = l0v; *(uint4*)(EL + ((bb + 16) ^ sw)) = l1v;
  }
  gbar(slots, r, 1, tid);
  for (int p = 0; p <= S + 2; ++p) {
    int t = p;
    if (t < S) {
      stage16(tid, hh + ((t - 1) & 1) * 16384, hl + ((t - 1) & 1) * 16384, AH, AL);
      __syncthreads();
      f32x4 s0h = {0,0,0,0}, s0l = {0,0,0,0}, s1h = {0,0,0,0}, s1l = {0,0,0,0};
      mm2<512>(AH, AL, whh, wlh, lane, s0h, s0l, s1h, s1l);
      mm2<256>(EH, EL, whi, wli, lane, s0h, s0l, s1h, s1l);
      f32x4 s0 = s0h + s0l, s1 = s1h + s1l;
      u16* Dh = hh + (t & 1) * 16384;
      u16* Dl = hl + (t & 1) * 16384;
      const bool last = (t == S - 1);
#pragma unroll
      for (int j = 0; j < 4; ++j) {
        float v = ftanh(s0[j] + bsum);
        unsigned ub = __builtin_bit_cast(unsigned, v);
        float lov = v - __builtin_bit_cast(float, ub & 0xFFFF0000u);
        int row = r0 + j;
        stg_sys_u16(Dh + (size_t)row * H + gcol, ub >> 16);
        stg_sys_u16(Dl + (size_t)row * H + gcol,
                    __builtin_bit_cast(unsigned, lov) >> 16);
        if (last) hnb[(size_t)row * H + gcol] = v;
        float v2 = ftanh(s1[j] + bsum);
        unsigned ub2 = __builtin_bit_cast(unsigned, v2);
        float lov2 = v2 - __builtin_bit_cast(float, ub2 & 0xFFFF0000u);
        int row2 = r0 + 16 + j;
        stg_sys_u16(Dh + (size_t)row2 * H + gcol, ub2 >> 16);
        stg_sys_u16(Dl + (size_t)row2 * H + gcol,
                    __builtin_bit_cast(unsigned, lov2) >> 16);
        if (last) hnb[(size_t)row2 * H + gcol] = v2;
      }
      // prefetch emb for t+1 (cached loads; off the sys-RT critical path)
      if (t + 1 < S) {
        __syncthreads();  // all waves done reading EH/EL
        int idx = x[(size_t)(gb0 + er) * S + (t + 1)];
        const float4* src = (const float4*)(emb + (size_t)idx * E + eq * 16);
        float4 v0 = src[0], v1 = src[1], v2 = src[2], v3 = src[3];
        uint4 h0v, h1v, l0v, l1v;
        cvt16(v0, v1, v2, v3, h0v, h1v, l0v, l1v);
        int bb = er * 512 + eq * 32, sw = (er & 7) << 4;
        *(uint4*)(EH + (bb ^ sw)) = h0v; *(uint4*)(EH + ((bb + 16) ^ sw)) = h1v;
        *(uint4*)(EL + (bb ^ sw)) = l0v; *(uint4*)(EL + ((bb + 16) ^ sw)) = l1v;
      }
    }
    gbar(slots, r, 2 + p, tid);
  }
}

// G (t=p-1): Gg[t] = b_ih1+b_hh1 + h0[t] @ W_ih1^T  (fp32)
__device__ void run_g(int tid, int lane, int w, unsigned* slots, int r,
                      const u16* h0h, const u16* h0l, float* Gg,
                      const float* b1, const float* b2,
                      const float* Wsrc, int tn, char* AH, char* AL) {
  short8 wh[16], wl[16];
  loadWfrag<512>(Wsrc, tn * 128 + w * 16, lane, wh, wl);
  gbar(slots, r, 1, tid);
  const int lc15 = lane & 15, r0 = (lane >> 4) * 4;
  const int gcol = tn * 128 + w * 16 + lc15;
  const float bsum = b1[gcol] + b2[gcol];
  for (int p = 0; p <= S + 2; ++p) {
    int t = p - 1;
    if (t >= 0 && t < S) {
      stage16(tid, h0h + (t & 1) * 16384, h0l + (t & 1) * 16384, AH, AL);
      __syncthreads();
      f32x4 s0h = {0,0,0,0}, s0l = {0,0,0,0}, s1h = {0,0,0,0}, s1l = {0,0,0,0};
      mm2<512>(AH, AL, wh, wl, lane, s0h, s0l, s1h, s1l);
      f32x4 s0 = s0h + s0l, s1 = s1h + s1l;
      float* D = Gg + (t & 1) * 16384;
#pragma unroll
      for (int j = 0; j < 4; ++j) {
        stg_sys_f32(D + (size_t)(r0 + j) * H + gcol, s0[j] + bsum);
        stg_sys_f32(D + (size_t)(r0 + 16 + j) * H + gcol, s1[j] + bsum);
      }
    }
    gbar(slots, r, 2 + p, tid);
  }
}

// h1 (t=p-2): h1[t] = tanh(Gg[t] + h1[t-1] @ W_hh1^T)
__device__ void run_h1(int tid, int lane, int w, unsigned* slots, int r,
                       u16* hh, u16* hl, const float* Gg, float* hnb,
                       const float* Wsrc, int tn, char* AH, char* AL) {
  short8 wh[16], wl[16];
  loadWfrag<512>(Wsrc, tn * 128 + w * 16, lane, wh, wl);
  gbar(slots, r, 1, tid);
  const int lc15 = lane & 15, r0 = (lane >> 4) * 4;
  const int gcol = tn * 128 + w * 16 + lc15;
  for (int p = 0; p <= S + 2; ++p) {
    int t = p - 2;
    if (t >= 0 && t < S) {
      const float* iq = Gg + (t & 1) * 16384 + (size_t)r0 * H + gcol;
      float iw[8];
      stage16i(tid, hh + ((t - 1) & 1) * 16384, hl + ((t - 1) & 1) * 16384,
               AH, AL, iq, iq + 2 * H, iq + 16 * H, iq + 18 * H, iw);
      __syncthreads();
      f32x4 s0h = {0,0,0,0}, s0l = {0,0,0,0}, s1h = {0,0,0,0}, s1l = {0,0,0,0};
      mm2<512>(AH, AL, wh, wl, lane, s0h, s0l, s1h, s1l);
      f32x4 s0 = s0h + s0l, s1 = s1h + s1l;
      u16* Dh = hh + (t & 1) * 16384;
      u16* Dl = hl + (t & 1) * 16384;
      const bool last = (t == S - 1);
#pragma unroll
      for (int j = 0; j < 4; ++j) {
        float v = ftanh(s0[j] + iw[2 * j]);         // iw order: rows r0+j pairs
        float v2 = ftanh(s1[j] + iw[2 * j + 1]);
        // NOTE: iw mapping: loads were {q0+0,q0+2048, q2+0,q2+2048, ...} =
        // rows {r0, r0+1, r0+2, r0+3, r0+16, r0+17, r0+18, r0+19}
        // so iw[0..3] = rows r0..r0+3, iw[4..7] = rows r0+16..r0+19.
        v  = ftanh(s0[j] + iw[j]);
        v2 = ftanh(s1[j] + iw[4 + j]);
        unsigned ub = __builtin_bit_cast(unsigned, v);
        float lov = v - __builtin_bit_cast(float, ub & 0xFFFF0000u);
        int row = r0 + j;
        stg_sys_u16(Dh + (size_t)row * H + gcol, ub >> 16);
        stg_sys_u16(Dl + (size_t)row * H + gcol,
                    __builtin_bit_cast(unsigned, lov) >> 16);
        if (last) hnb[(size_t)row * H + gcol] = v;
        unsigned ub2 = __builtin_bit_cast(unsigned, v2);
        float lov2 = v2 - __builtin_bit_cast(float, ub2 & 0xFFFF0000u);
        int row2 = r0 + 16 + j;
        stg_sys_u16(Dh + (size_t)row2 * H + gcol, ub2 >> 16);
        stg_sys_u16(Dl + (size_t)row2 * H + gcol,
                    __builtin_bit_cast(unsigned, lov2) >> 16);
        if (last) hnb[(size_t)row2 * H + gcol] = v2;
      }
    }
    gbar(slots, r, 2 + p, tid);
  }
}

// out (t=p-3): out[t] = b_out + h1[t] @ W_out^T
__device__ void run_out(int tid, int lane, int w, unsigned* slots, int r,
                        const u16* h1h, const u16* h1l, float* out,
                        const float* b_out, const float* Wsrc, int gb0,
                        char* AH, char* AL) {
  short8 wh[16], wl[16];
  loadWfrag<512>(Wsrc, w * 16, lane, wh, wl);
  gbar(slots, r, 1, tid);
  const int lc15 = lane & 15, r0 = (lane >> 4) * 4;
  const int gcol = w * 16 + lc15;
  const float bv = b_out[gcol];
  for (int p = 0; p <= S + 2; ++p) {
    int t = p - 3;
    if (t >= 0 && t < S) {
      stage16(tid, h1h + (t & 1) * 16384, h1l + (t & 1) * 16384, AH, AL);
      __syncthreads();
      f32x4 s0h = {0,0,0,0}, s0l = {0,0,0,0}, s1h = {0,0,0,0}, s1l = {0,0,0,0};
      mm2<512>(AH, AL, wh, wl, lane, s0h, s0l, s1h, s1l);
      f32x4 s0 = s0h + s0l, s1 = s1h + s1l;
#pragma unroll
      for (int j = 0; j < 4; ++j) {
        out[((size_t)(gb0 + r0 + j) * S + t) * V + gcol] = s0[j] + bv;
        out[((size_t)(gb0 + r0 + 16 + j) * S + t) * V + gcol] = s1[j] + bv;
      }
    }
    gbar(slots, r, 2 + p, tid);
  }
}

// Grouping by blockIdx (placement-independent correctness, G16).
// 4 groups x 32 batch rows; 13 roles per group (512-thread WGs):
//  r [0,4): h0 t=p (emb-merged) | r [4,8): G t=p-1 | r [8,12): h1 t=p-2
//  r 12: logits t=p-3
__global__ void __launch_bounds__(NT, 1) rnn_pers(
    const int* __restrict__ x, const float* __restrict__ emb,
    const float* __restrict__ W_ih0, const float* __restrict__ b_ih0,
    const float* __restrict__ W_hh0, const float* __restrict__ b_hh0,
    const float* __restrict__ W_ih1, const float* __restrict__ b_ih1,
    const float* __restrict__ W_hh1, const float* __restrict__ b_hh1,
    const float* __restrict__ W_out, const float* __restrict__ b_out,
    float* __restrict__ out, float* __restrict__ ws)
{
  extern __shared__ char lds[];
  char* AH = lds;              // 32KB: [32][512] bf16-hi
  char* AL = lds + 32768;      // 32KB: lo
  char* EH = lds + 65536;      // 16KB: emb [32][256] bf16-hi
  char* EL = lds + 81920;      // 16KB: lo

  const int tid = threadIdx.x;
  const int g = blockIdx.x >> 4;
  const int r = blockIdx.x & 15;
  if (r >= WPG) return;

  unsigned* slots = (unsigned*)ws + (size_t)g * 64;
  float* base = ws + 1024 + (size_t)g * 98304;
  float* Gg = base;                  // fp32 [2][32][512]
  u16* h0h = (u16*)(base + 32768);   // [2][32][512] u16 planes
  u16* h0l = h0h + 32768;
  u16* h1h = h0h + 65536;
  u16* h1l = h0h + 98304;
  const int gb0 = g * GB;

  // Zero h-state planes (both slots, 4 planes = 65536 u32), system scope.
  {
    unsigned* zp = (unsigned*)h0h;
    for (int i = r * NT + tid; i < 65536; i += WPG * NT) stg_sys_u32(zp + i, 0u);
  }

  const int lane = tid & 63, w = tid >> 6;
  float* hn = out + (size_t)B * S * V;

  if (r < 4)
    run_h0(tid, lane, w, slots, r, h0h, h0l, x, emb, b_ih0, b_hh0,
           hn + (size_t)gb0 * H, W_hh0, W_ih0, r, gb0, AH, AL, EH, EL);
  else if (r < 8)
    run_g(tid, lane, w, slots, r, h0h, h0l, Gg, b_ih1, b_hh1,
          W_ih1, r - 4, AH, AL);
  else if (r < 12)
    run_h1(tid, lane, w, slots, r, h1h, h1l, Gg,
           hn + (size_t)B * H + (size_t)gb0 * H, W_hh1, r - 8, AH, AL);
  else
    run_out(tid, lane, w, slots, r, h1h, h1l, out, b_out, W_out, gb0, AH, AL);
}

extern "C" void kernel_launch(void* const* d_in, const int* in_sizes, int n_in,
                              void* d_out, int out_size, void* d_ws, size_t ws_size,
                              hipStream_t stream) {
  const int*   x     = (const int*)d_in[0];
  const float* emb   = (const float*)d_in[1];
  const float* W_ih0 = (const float*)d_in[2];
  const float* b_ih0 = (const float*)d_in[3];
  const float* W_hh0 = (const float*)d_in[4];
  const float* b_hh0 = (const float*)d_in[5];
  const float* W_ih1 = (const float*)d_in[6];
  const float* b_ih1 = (const float*)d_in[7];
  const float* W_hh1 = (const float*)d_in[8];
  const float* b_hh1 = (const float*)d_in[9];
  const float* W_out = (const float*)d_in[10];
  const float* b_out = (const float*)d_in[11];
  float* out = (float*)d_out;
  float* ws  = (float*)d_ws;

  hipFuncSetAttribute((const void*)rnn_pers,
                      hipFuncAttributeMaxDynamicSharedMemorySize, (int)LDS_BYTES);
  hipMemsetAsync(ws, 0, 4096, stream);  // barrier flags

  void* args[] = { &x, &emb, &W_ih0, &b_ih0, &W_hh0, &b_hh0, &W_ih1, &b_ih1,
                   &W_hh1, &b_hh1, &W_out, &b_out, &out, &ws };
  hipLaunchCooperativeKernel((const void*)rnn_pers, dim3(NWG), dim3(NT),
                             args, LDS_BYTES, stream);
}

// Round 14
// 6056.075 us; speedup vs baseline: 1.5663x; 1.5663x over previous
//
#include <hip/hip_runtime.h>

// Problem sizes (fixed by the reference)
constexpr int B = 128, S = 1024, E = 256, H = 512, V = 128;
constexpr int NGROUP = 4, WPG = 15, NWG = 64;   // 4 groups x 16 slots (15 live)
constexpr int GB = B / NGROUP;                  // 32 batch rows per group
constexpr int NT = 512;                         // 8 waves per WG
constexpr unsigned LDS_BYTES = 65536;           // AH/AL 32KB+32KB (Ain aliases)

using short8 = __attribute__((ext_vector_type(8))) short;
using f32x4  = __attribute__((ext_vector_type(4))) float;
using u16    = unsigned short;

#define MFMA_B16(a, b, c) __builtin_amdgcn_mfma_f32_16x16x32_bf16((a), (b), (c), 0, 0, 0)

// ---- bf16 hi/lo split helpers (v = hi + lo, ~2^-16 rel error) ---------------
__device__ __forceinline__ unsigned pk(float a, float b) {
  return (__builtin_bit_cast(unsigned, b) & 0xFFFF0000u) |
         (__builtin_bit_cast(unsigned, a) >> 16);
}
__device__ __forceinline__ float hif(float a) {
  return __builtin_bit_cast(float, __builtin_bit_cast(unsigned, a) & 0xFFFF0000u);
}
__device__ __forceinline__ void cvt16(const float4& v0, const float4& v1,
                                      const float4& v2, const float4& v3,
                                      uint4& h0, uint4& h1, uint4& l0, uint4& l1) {
  h0 = make_uint4(pk(v0.x, v0.y), pk(v0.z, v0.w), pk(v1.x, v1.y), pk(v1.z, v1.w));
  h1 = make_uint4(pk(v2.x, v2.y), pk(v2.z, v2.w), pk(v3.x, v3.y), pk(v3.z, v3.w));
  l0 = make_uint4(pk(v0.x - hif(v0.x), v0.y - hif(v0.y)),
                  pk(v0.z - hif(v0.z), v0.w - hif(v0.w)),
                  pk(v1.x - hif(v1.x), v1.y - hif(v1.y)),
                  pk(v1.z - hif(v1.z), v1.w - hif(v1.w)));
  l1 = make_uint4(pk(v2.x - hif(v2.x), v2.y - hif(v2.y)),
                  pk(v2.z - hif(v2.z), v2.w - hif(v2.w)),
                  pk(v3.x - hif(v3.x), v3.y - hif(v3.y)),
                  pk(v3.z - hif(v3.z), v3.w - hif(v3.w)));
}

// fast tanh via hardware exp (round-8/12 proven: same absmax as tanhf)
__device__ __forceinline__ float ftanh(float x) {
  float e = __expf(2.0f * x);
  return 1.0f - 2.0f * __builtin_amdgcn_rcpf(e + 1.0f);
}

// ---- system-scope (cross-XCD, fence-free) memory helpers --------------------
__device__ __forceinline__ void stg_sys_f32(float* p, float v) {
  asm volatile("global_store_dword %0, %1, off sc0 sc1" :: "v"(p), "v"(v) : "memory");
}
__device__ __forceinline__ void stg_sys_u32(unsigned* p, unsigned v) {
  asm volatile("global_store_dword %0, %1, off sc0 sc1" :: "v"(p), "v"(v) : "memory");
}
__device__ __forceinline__ void stg_sys_u16(u16* p, unsigned v) {
  asm volatile("global_store_short %0, %1, off sc0 sc1" :: "v"(p), "v"(v) : "memory");
}

// Group barrier (round-7/12 proven primitive): per-WG flag slot, no RMW, no
// cache-maintenance fences. vmcnt(0) drains own sc stores; tid0 publishes;
// wave0 lanes poll the 15 slots with s_sleep backoff.
__device__ __forceinline__ void gbar(unsigned* slots, int r, unsigned target, int tid) {
  asm volatile("s_waitcnt vmcnt(0)" ::: "memory");
  __syncthreads();
  if (tid < 64) {
    if (tid == 0)
      asm volatile("global_store_dword %0, %1, off sc0 sc1"
                   :: "v"(slots + r), "v"(target) : "memory");
    for (;;) {
      unsigned v = target;
      if (tid < WPG)
        asm volatile("global_load_dword %0, %1, off sc0 sc1\n\ts_waitcnt vmcnt(0)"
                     : "=v"(v) : "v"(slots + tid) : "memory");
      if (__all((int)(v >= target))) break;
      __builtin_amdgcn_s_sleep(1);
    }
  }
  __syncthreads();
}

// ---- W fragment -> registers (loaded once) ----------------------------------
template <int KK>
__device__ __forceinline__ void loadWfrag(const float* W, int col0, int lane,
                                          short8* wh, short8* wl) {
  const int lc = col0 + (lane & 15);
  const int q = lane >> 4;
#pragma unroll
  for (int ks = 0; ks < KK / 32; ++ks) {
    const float* src = W + (size_t)lc * KK + ks * 32 + q * 8;
    float4 a = *(const float4*)src;
    float4 b = *(const float4*)(src + 4);
    uint4 h = make_uint4(pk(a.x, a.y), pk(a.z, a.w), pk(b.x, b.y), pk(b.z, b.w));
    uint4 l = make_uint4(pk(a.x - hif(a.x), a.y - hif(a.y)),
                         pk(a.z - hif(a.z), a.w - hif(a.w)),
                         pk(b.x - hif(b.x), b.y - hif(b.y)),
                         pk(b.z - hif(b.z), b.w - hif(b.w)));
    wh[ks] = __builtin_bit_cast(short8, h);
    wl[ks] = __builtin_bit_cast(short8, l);
  }
}

// ---- A staging: bf16 hi/lo state planes ([32][512] u16, 32KB each) -> LDS ---
// (r13-proven) 512 threads x 4 chunks x 16B per plane, single vmcnt(0).
__device__ __forceinline__ void stage16(int tid, const u16* Ph, const u16* Pl,
                                        char* AH, char* AL) {
  int off[4], lof[4];
#pragma unroll
  for (int it = 0; it < 4; ++it) {
    int s = tid + it * NT, rr = s >> 6, ks = s & 63;
    off[it] = rr * 1024 + ks * 16;
    lof[it] = off[it] ^ ((rr & 7) << 4);
  }
  const char* gh = (const char*)Ph;
  const char* gl = (const char*)Pl;
  float4 a0, a1, a2, a3, b0, b1, b2, b3;
  asm volatile(
      "global_load_dwordx4 %0, %8, off sc0 sc1\n\t"
      "global_load_dwordx4 %1, %9, off sc0 sc1\n\t"
      "global_load_dwordx4 %2, %10, off sc0 sc1\n\t"
      "global_load_dwordx4 %3, %11, off sc0 sc1\n\t"
      "global_load_dwordx4 %4, %12, off sc0 sc1\n\t"
      "global_load_dwordx4 %5, %13, off sc0 sc1\n\t"
      "global_load_dwordx4 %6, %14, off sc0 sc1\n\t"
      "global_load_dwordx4 %7, %15, off sc0 sc1\n\t"
      "s_waitcnt vmcnt(0)"
      : "=&v"(a0), "=&v"(a1), "=&v"(a2), "=&v"(a3),
        "=&v"(b0), "=&v"(b1), "=&v"(b2), "=&v"(b3)
      : "v"(gh + off[0]), "v"(gh + off[1]), "v"(gh + off[2]), "v"(gh + off[3]),
        "v"(gl + off[0]), "v"(gl + off[1]), "v"(gl + off[2]), "v"(gl + off[3])
      : "memory");
  *(float4*)(AH + lof[0]) = a0; *(float4*)(AH + lof[1]) = a1;
  *(float4*)(AH + lof[2]) = a2; *(float4*)(AH + lof[3]) = a3;
  *(float4*)(AL + lof[0]) = b0; *(float4*)(AL + lof[1]) = b1;
  *(float4*)(AL + lof[2]) = b2; *(float4*)(AL + lof[3]) = b3;
}

// (r13-proven) Same + 8 fp32 init scalars: rows {r0..r0+3} via q0/q2 with
// offset:0/2048 and rows {r0+16..r0+19} via q16/q18. iw[j]=row r0+j,
// iw[4+j]=row r0+16+j. Single vmcnt(0) for all 16 loads.
__device__ __forceinline__ void stage16i(int tid, const u16* Ph, const u16* Pl,
                                         char* AH, char* AL,
                                         const float* q0, const float* q2,
                                         const float* q16, const float* q18,
                                         float* iw) {
  int off[4], lof[4];
#pragma unroll
  for (int it = 0; it < 4; ++it) {
    int s = tid + it * NT, rr = s >> 6, ks = s & 63;
    off[it] = rr * 1024 + ks * 16;
    lof[it] = off[it] ^ ((rr & 7) << 4);
  }
  const char* gh = (const char*)Ph;
  const char* gl = (const char*)Pl;
  float4 a0, a1, a2, a3, b0, b1, b2, b3;
  asm volatile(
      "global_load_dword %8, %20, off sc0 sc1\n\t"
      "global_load_dword %9, %20, off offset:2048 sc0 sc1\n\t"
      "global_load_dword %10, %21, off sc0 sc1\n\t"
      "global_load_dword %11, %21, off offset:2048 sc0 sc1\n\t"
      "global_load_dword %12, %22, off sc0 sc1\n\t"
      "global_load_dword %13, %22, off offset:2048 sc0 sc1\n\t"
      "global_load_dword %14, %23, off sc0 sc1\n\t"
      "global_load_dword %15, %23, off offset:2048 sc0 sc1\n\t"
      "global_load_dwordx4 %0, %16, off sc0 sc1\n\t"
      "global_load_dwordx4 %1, %17, off sc0 sc1\n\t"
      "global_load_dwordx4 %2, %18, off sc0 sc1\n\t"
      "global_load_dwordx4 %3, %19, off sc0 sc1\n\t"
      "global_load_dwordx4 %4, %24, off sc0 sc1\n\t"
      "global_load_dwordx4 %5, %25, off sc0 sc1\n\t"
      "global_load_dwordx4 %6, %26, off sc0 sc1\n\t"
      "global_load_dwordx4 %7, %27, off sc0 sc1\n\t"
      "s_waitcnt vmcnt(0)"
      : "=&v"(a0), "=&v"(a1), "=&v"(a2), "=&v"(a3),
        "=&v"(b0), "=&v"(b1), "=&v"(b2), "=&v"(b3),
        "=&v"(iw[0]), "=&v"(iw[1]), "=&v"(iw[2]), "=&v"(iw[3]),
        "=&v"(iw[4]), "=&v"(iw[5]), "=&v"(iw[6]), "=&v"(iw[7])
      : "v"(gh + off[0]), "v"(gh + off[1]), "v"(gh + off[2]), "v"(gh + off[3]),
        "v"(q0), "v"(q2), "v"(q16), "v"(q18),
        "v"(gl + off[0]), "v"(gl + off[1]), "v"(gl + off[2]), "v"(gl + off[3])
      : "memory");
  *(float4*)(AH + lof[0]) = a0; *(float4*)(AH + lof[1]) = a1;
  *(float4*)(AH + lof[2]) = a2; *(float4*)(AH + lof[3]) = a3;
  *(float4*)(AL + lof[0]) = b0; *(float4*)(AL + lof[1]) = b1;
  *(float4*)(AL + lof[2]) = b2; *(float4*)(AL + lof[3]) = b3;
}

// ---- bf16x3 MFMA, 2 row-tiles (rows rr, rr+16), accumulating (r13-proven) ---
template <int KK>
__device__ __forceinline__ void mm2(const char* AH, const char* AL,
                                    const short8* wh, const short8* wl,
                                    int lane, f32x4& s0h, f32x4& s0l,
                                    f32x4& s1h, f32x4& s1l) {
  constexpr int ROWB = KK * 2;
  const int rr = lane & 15;
  const int kq = (lane >> 4) * 16;
  const int swa = (rr & 7) << 4;   // same swizzle for rr and rr+16 (16%8==0)
#pragma unroll
  for (int ks = 0; ks < KK / 32; ++ks) {
    int ka0 = rr * ROWB + ks * 64 + kq;
    int ka1 = ka0 + 16 * ROWB;
    short8 ah0 = *(const short8*)(AH + (ka0 ^ swa));
    short8 al0 = *(const short8*)(AL + (ka0 ^ swa));
    short8 ah1 = *(const short8*)(AH + (ka1 ^ swa));
    short8 al1 = *(const short8*)(AL + (ka1 ^ swa));
    s0h = MFMA_B16(ah0, wh[ks], s0h);
    s0l = MFMA_B16(ah0, wl[ks], s0l);
    s0l = MFMA_B16(al0, wh[ks], s0l);
    s1h = MFMA_B16(ah1, wh[ks], s1h);
    s1l = MFMA_B16(ah1, wl[ks], s1l);
    s1l = MFMA_B16(al1, wh[ks], s1l);
  }
}

// store one tanh'd value pair to hi/lo planes (+ optional h_n duplicate)
__device__ __forceinline__ void store_h(u16* Dh, u16* Dl, float* hnb, bool last,
                                        int row, int gcol, float v) {
  unsigned ub = __builtin_bit_cast(unsigned, v);
  float lov = v - __builtin_bit_cast(float, ub & 0xFFFF0000u);
  stg_sys_u16(Dh + (size_t)row * H + gcol, ub >> 16);
  stg_sys_u16(Dl + (size_t)row * H + gcol, __builtin_bit_cast(unsigned, lov) >> 16);
  if (last) hnb[(size_t)row * H + gcol] = v;
}

// ---- per-role phase loops (r12 structure, 32-row groups) --------------------
// role h (h0: dt=1 init from Ain, h1: dt=3 init from Gg)
__device__ void run_h(int tid, int lane, int w, unsigned* slots, int r, int dt,
                      u16* hh, u16* hl, const float* imb, float* hnb,
                      const float* Wsrc, int tn, char* AH, char* AL) {
  short8 wh[16], wl[16];
  loadWfrag<512>(Wsrc, tn * 128 + w * 16, lane, wh, wl);
  gbar(slots, r, 1, tid);
  const int lc15 = lane & 15, r0 = (lane >> 4) * 4;
  const int gcol = tn * 128 + w * 16 + lc15;
  for (int p = 0; p <= S + 3; ++p) {
    int t = p - dt;
    if (t >= 0 && t < S) {
      const float* iq = imb + (t & 1) * 16384 + (size_t)r0 * H + gcol;
      float iw[8];
      stage16i(tid, hh + ((t - 1) & 1) * 16384, hl + ((t - 1) & 1) * 16384,
               AH, AL, iq, iq + 2 * H, iq + 16 * H, iq + 18 * H, iw);
      __syncthreads();
      f32x4 s0h = {0,0,0,0}, s0l = {0,0,0,0}, s1h = {0,0,0,0}, s1l = {0,0,0,0};
      mm2<512>(AH, AL, wh, wl, lane, s0h, s0l, s1h, s1l);
      f32x4 s0 = s0h + s0l, s1 = s1h + s1l;
      u16* Dh = hh + (t & 1) * 16384;
      u16* Dl = hl + (t & 1) * 16384;
      const bool last = (t == S - 1);
#pragma unroll
      for (int j = 0; j < 4; ++j) {
        store_h(Dh, Dl, hnb, last, r0 + j, gcol, ftanh(s0[j] + iw[j]));
        store_h(Dh, Dl, hnb, last, r0 + 16 + j, gcol, ftanh(s1[j] + iw[4 + j]));
      }
    }
    gbar(slots, r, 2 + p, tid);
  }
}

// role G (t=p-2): Gg[t] = b_ih1+b_hh1 + h0[t] @ W_ih1^T  (fp32)
__device__ void run_g(int tid, int lane, int w, unsigned* slots, int r,
                      const u16* h0h, const u16* h0l, float* Gg,
                      const float* b1, const float* b2,
                      const float* Wsrc, int tn, char* AH, char* AL) {
  short8 wh[16], wl[16];
  loadWfrag<512>(Wsrc, tn * 128 + w * 16, lane, wh, wl);
  gbar(slots, r, 1, tid);
  const int lc15 = lane & 15, r0 = (lane >> 4) * 4;
  const int gcol = tn * 128 + w * 16 + lc15;
  const float bsum = b1[gcol] + b2[gcol];
  for (int p = 0; p <= S + 3; ++p) {
    int t = p - 2;
    if (t >= 0 && t < S) {
      stage16(tid, h0h + (t & 1) * 16384, h0l + (t & 1) * 16384, AH, AL);
      __syncthreads();
      f32x4 s0h = {0,0,0,0}, s0l = {0,0,0,0}, s1h = {0,0,0,0}, s1l = {0,0,0,0};
      mm2<512>(AH, AL, wh, wl, lane, s0h, s0l, s1h, s1l);
      f32x4 s0 = s0h + s0l, s1 = s1h + s1l;
      float* D = Gg + (t & 1) * 16384;
#pragma unroll
      for (int j = 0; j < 4; ++j) {
        stg_sys_f32(D + (size_t)(r0 + j) * H + gcol, s0[j] + bsum);
        stg_sys_f32(D + (size_t)(r0 + 16 + j) * H + gcol, s1[j] + bsum);
      }
    }
    gbar(slots, r, 2 + p, tid);
  }
}

// role Ain (t=p): Ain[t] = b_ih0+b_hh0 + emb[x[:,t]] @ W_ih0^T  (256 cols/WG)
__device__ void run_ain(int tid, int lane, int w, unsigned* slots, int r,
                        const int* x, const float* emb, float* Ain,
                        const float* b1, const float* b2,
                        const float* Wsrc, int a, int gb0, char* EH, char* EL) {
  short8 whA[8], wlA[8], whB[8], wlB[8];
  const int col0 = a * 256 + w * 32;
  loadWfrag<256>(Wsrc, col0, lane, whA, wlA);
  loadWfrag<256>(Wsrc, col0 + 16, lane, whB, wlB);
  gbar(slots, r, 1, tid);
  const int lc15 = lane & 15, r0 = (lane >> 4) * 4;
  const int gcolA = col0 + lc15, gcolB = gcolA + 16;
  const float bsA = b1[gcolA] + b2[gcolA], bsB = b1[gcolB] + b2[gcolB];
  const int er = tid >> 4, eq = tid & 15;  // 32 rows x 16 chunks = 512 threads
  for (int p = 0; p <= S + 3; ++p) {
    int t = p;
    if (t < S) {
      {
        int idx = x[(size_t)(gb0 + er) * S + t];
        const float4* src = (const float4*)(emb + (size_t)idx * E + eq * 16);
        float4 v0 = src[0], v1 = src[1], v2 = src[2], v3 = src[3];
        uint4 h0v, h1v, l0v, l1v;
        cvt16(v0, v1, v2, v3, h0v, h1v, l0v, l1v);
        int bb = er * 512 + eq * 32, sw = (er & 7) << 4;
        *(uint4*)(EH + (bb ^ sw)) = h0v; *(uint4*)(EH + ((bb + 16) ^ sw)) = h1v;
        *(uint4*)(EL + (bb ^ sw)) = l0v; *(uint4*)(EL + ((bb + 16) ^ sw)) = l1v;
      }
      __syncthreads();
      f32x4 sAh = {0,0,0,0}, sAl = {0,0,0,0}, sA1h = {0,0,0,0}, sA1l = {0,0,0,0};
      mm2<256>(EH, EL, whA, wlA, lane, sAh, sAl, sA1h, sA1l);
      f32x4 sA0 = sAh + sAl, sA1 = sA1h + sA1l;
      f32x4 sBh = {0,0,0,0}, sBl = {0,0,0,0}, sB1h = {0,0,0,0}, sB1l = {0,0,0,0};
      mm2<256>(EH, EL, whB, wlB, lane, sBh, sBl, sB1h, sB1l);
      f32x4 sB0 = sBh + sBl, sB1 = sB1h + sB1l;
      float* D = Ain + (t & 1) * 16384;
#pragma unroll
      for (int j = 0; j < 4; ++j) {
        stg_sys_f32(D + (size_t)(r0 + j) * H + gcolA, sA0[j] + bsA);
        stg_sys_f32(D + (size_t)(r0 + 16 + j) * H + gcolA, sA1[j] + bsA);
        stg_sys_f32(D + (size_t)(r0 + j) * H + gcolB, sB0[j] + bsB);
        stg_sys_f32(D + (size_t)(r0 + 16 + j) * H + gcolB, sB1[j] + bsB);
      }
      __syncthreads();  // protect EH/EL before next-phase restage
    }
    gbar(slots, r, 2 + p, tid);
  }
}

// role logits (t=p-4): out[t] = b_out + h1[t] @ W_out^T (one WG, 128 V-cols)
__device__ void run_out(int tid, int lane, int w, unsigned* slots, int r,
                        const u16* h1h, const u16* h1l, float* out,
                        const float* b_out, const float* Wsrc, int gb0,
                        char* AH, char* AL) {
  short8 wh[16], wl[16];
  loadWfrag<512>(Wsrc, w * 16, lane, wh, wl);
  gbar(slots, r, 1, tid);
  const int lc15 = lane & 15, r0 = (lane >> 4) * 4;
  const int gcol = w * 16 + lc15;
  const float bv = b_out[gcol];
  for (int p = 0; p <= S + 3; ++p) {
    int t = p - 4;
    if (t >= 0 && t < S) {
      stage16(tid, h1h + (t & 1) * 16384, h1l + (t & 1) * 16384, AH, AL);
      __syncthreads();
      f32x4 s0h = {0,0,0,0}, s0l = {0,0,0,0}, s1h = {0,0,0,0}, s1l = {0,0,0,0};
      mm2<512>(AH, AL, wh, wl, lane, s0h, s0l, s1h, s1l);
      f32x4 s0 = s0h + s0l, s1 = s1h + s1l;
#pragma unroll
      for (int j = 0; j < 4; ++j) {
        out[((size_t)(gb0 + r0 + j) * S + t) * V + gcol] = s0[j] + bv;
        out[((size_t)(gb0 + r0 + 16 + j) * S + t) * V + gcol] = s1[j] + bv;
      }
    }
    gbar(slots, r, 2 + p, tid);
  }
}

// Grouping by blockIdx (placement-independent correctness, G16).
// 4 groups x 32 batch rows; 15 roles per group (512-thread WGs), r12 schedule:
//  r [0,4): h0 t=p-1 | r [4,8): G t=p-2 | r [8,12): h1 t=p-3
//  r [12,14): Ain t=p (256 cols) | r 14: logits t=p-4
__global__ void __launch_bounds__(NT, 1) rnn_pers(
    const int* __restrict__ x, const float* __restrict__ emb,
    const float* __restrict__ W_ih0, const float* __restrict__ b_ih0,
    const float* __restrict__ W_hh0, const float* __restrict__ b_hh0,
    const float* __restrict__ W_ih1, const float* __restrict__ b_ih1,
    const float* __restrict__ W_hh1, const float* __restrict__ b_hh1,
    const float* __restrict__ W_out, const float* __restrict__ b_out,
    float* __restrict__ out, float* __restrict__ ws)
{
  extern __shared__ char lds[];
  char* AH = lds;              // 32KB: [32][512] bf16-hi   (Ain role: EH 16KB)
  char* AL = lds + 32768;      // 32KB: lo                  (Ain role: EL)

  const int tid = threadIdx.x;
  const int g = blockIdx.x >> 4;
  const int r = blockIdx.x & 15;
  if (r >= WPG) return;

  unsigned* slots = (unsigned*)ws + (size_t)g * 64;
  float* base = ws + 1024 + (size_t)g * 131072;
  float* Ain = base;                 // fp32 [2][32][512]
  float* Gg  = base + 32768;         // fp32 [2][32][512]
  u16* h0h = (u16*)(base + 65536);   // [2][32][512] u16 planes x4
  u16* h0l = h0h + 32768;
  u16* h1h = h0h + 65536;
  u16* h1l = h0h + 98304;
  const int gb0 = g * GB;

  // Zero h-state planes (both slots, 4 planes = 65536 u32), system scope.
  {
    unsigned* zp = (unsigned*)h0h;
    for (int i = r * NT + tid; i < 65536; i += WPG * NT) stg_sys_u32(zp + i, 0u);
  }

  const int lane = tid & 63, w = tid >> 6;
  float* hn = out + (size_t)B * S * V;

  if (r < 4)
    run_h(tid, lane, w, slots, r, 1, h0h, h0l, Ain,
          hn + (size_t)gb0 * H, W_hh0, r, AH, AL);
  else if (r < 8)
    run_g(tid, lane, w, slots, r, h0h, h0l, Gg, b_ih1, b_hh1,
          W_ih1, r - 4, AH, AL);
  else if (r < 12)
    run_h(tid, lane, w, slots, r, 3, h1h, h1l, Gg,
          hn + (size_t)B * H + (size_t)gb0 * H, W_hh1, r - 8, AH, AL);
  else if (r < 14)
    run_ain(tid, lane, w, slots, r, x, emb, Ain, b_ih0, b_hh0,
            W_ih0, r - 12, gb0, AH, AL);
  else
    run_out(tid, lane, w, slots, r, h1h, h1l, out, b_out, W_out, gb0, AH, AL);
}

extern "C" void kernel_launch(void* const* d_in, const int* in_sizes, int n_in,
                              void* d_out, int out_size, void* d_ws, size_t ws_size,
                              hipStream_t stream) {
  const int*   x     = (const int*)d_in[0];
  const float* emb   = (const float*)d_in[1];
  const float* W_ih0 = (const float*)d_in[2];
  const float* b_ih0 = (const float*)d_in[3];
  const float* W_hh0 = (const float*)d_in[4];
  const float* b_hh0 = (const float*)d_in[5];
  const float* W_ih1 = (const float*)d_in[6];
  const float* b_ih1 = (const float*)d_in[7];
  const float* W_hh1 = (const float*)d_in[8];
  const float* b_hh1 = (const float*)d_in[9];
  const float* W_out = (const float*)d_in[10];
  const float* b_out = (const float*)d_in[11];
  float* out = (float*)d_out;
  float* ws  = (float*)d_ws;

  hipFuncSetAttribute((const void*)rnn_pers,
                      hipFuncAttributeMaxDynamicSharedMemorySize, (int)LDS_BYTES);
  hipMemsetAsync(ws, 0, 4096, stream);  // barrier flags

  void* args[] = { &x, &emb, &W_ih0, &b_ih0, &W_hh0, &b_hh0, &W_ih1, &b_ih1,
                   &W_hh1, &b_hh1, &W_out, &b_out, &out, &ws };
  hipLaunchCooperativeKernel((const void*)rnn_pers, dim3(NWG), dim3(NT),
                             args, LDS_BYTES, stream);
}

// Round 17
// 3526.925 us; speedup vs baseline: 2.6894x; 1.7171x over previous
//
#include <hip/hip_runtime.h>

// Problem sizes (fixed by the reference)
constexpr int B = 128, S = 1024, E = 256, H = 512, V = 128;
constexpr int NGROUP = 8, WPG = 15, NWG = 128;  // 8 groups x 16 slots (15 live)
constexpr int GB = B / NGROUP;                  // 16 batch rows per group
constexpr int NT = 512;                         // threads per WG (8 waves)
constexpr int FSTRIDE = 16;                     // flag slot stride (u32) = 64B line
constexpr unsigned LDS_BYTES = 32768;           // AH 16KB + AL 16KB

using short8 = __attribute__((ext_vector_type(8))) short;   // 8 bf16 = 4 VGPRs
using f32x4  = __attribute__((ext_vector_type(4))) float;   // MFMA acc
using u16    = unsigned short;

#define MFMA_B16(a, b, c) __builtin_amdgcn_mfma_f32_16x16x32_bf16((a), (b), (c), 0, 0, 0)

// ---- bf16 hi/lo split helpers (v = hi + lo, ~2^-16 rel error) ---------------
__device__ __forceinline__ unsigned pk(float a, float b) {
  return (__builtin_bit_cast(unsigned, b) & 0xFFFF0000u) |
         (__builtin_bit_cast(unsigned, a) >> 16);
}
__device__ __forceinline__ float hif(float a) {
  return __builtin_bit_cast(float, __builtin_bit_cast(unsigned, a) & 0xFFFF0000u);
}
__device__ __forceinline__ void cvt16(const float4& v0, const float4& v1,
                                      const float4& v2, const float4& v3,
                                      uint4& h0, uint4& h1, uint4& l0, uint4& l1) {
  h0 = make_uint4(pk(v0.x, v0.y), pk(v0.z, v0.w), pk(v1.x, v1.y), pk(v1.z, v1.w));
  h1 = make_uint4(pk(v2.x, v2.y), pk(v2.z, v2.w), pk(v3.x, v3.y), pk(v3.z, v3.w));
  l0 = make_uint4(pk(v0.x - hif(v0.x), v0.y - hif(v0.y)),
                  pk(v0.z - hif(v0.z), v0.w - hif(v0.w)),
                  pk(v1.x - hif(v1.x), v1.y - hif(v1.y)),
                  pk(v1.z - hif(v1.z), v1.w - hif(v1.w)));
  l1 = make_uint4(pk(v2.x - hif(v2.x), v2.y - hif(v2.y)),
                  pk(v2.z - hif(v2.z), v2.w - hif(v2.w)),
                  pk(v3.x - hif(v3.x), v3.y - hif(v3.y)),
                  pk(v3.z - hif(v3.z), v3.w - hif(v3.w)));
}

// fast tanh via hardware exp (round-8/12 proven: same absmax as tanhf)
__device__ __forceinline__ float ftanh(float x) {
  float e = __expf(2.0f * x);
  return 1.0f - 2.0f * __builtin_amdgcn_rcpf(e + 1.0f);
}

// ---- system-scope (cross-XCD, fence-free) memory helpers --------------------
__device__ __forceinline__ void stg_sys_f32(float* p, float v) {
  asm volatile("global_store_dword %0, %1, off sc0 sc1" :: "v"(p), "v"(v) : "memory");
}
__device__ __forceinline__ void stg_sys_u32(unsigned* p, unsigned v) {
  asm volatile("global_store_dword %0, %1, off sc0 sc1" :: "v"(p), "v"(v) : "memory");
}
__device__ __forceinline__ void stg_sys_u16(u16* p, unsigned v) {
  asm volatile("global_store_short %0, %1, off sc0 sc1" :: "v"(p), "v"(v) : "memory");
}

// Group barrier (r7/r12-proven structure) with CACHELINE-SPREAD flag slots:
// slot r lives at slots[r*FSTRIDE] (64B apart) -> no line ping-pong between
// the 15 writers / 15-lane pollers. vmcnt(0) drains own sc stores; tid0
// publishes; wave0 lanes poll with s_sleep backoff. Cap -> fail-visible.
__device__ __forceinline__ void gbar(unsigned* slots, int r, unsigned target, int tid) {
  asm volatile("s_waitcnt vmcnt(0)" ::: "memory");
  __syncthreads();
  if (tid < 64) {
    if (tid == 0)
      asm volatile("global_store_dword %0, %1, off sc0 sc1"
                   :: "v"(slots + r * FSTRIDE), "v"(target) : "memory");
    int cap = 0;
    for (;;) {
      unsigned v = target;
      if (tid < WPG)
        asm volatile("global_load_dword %0, %1, off sc0 sc1\n\ts_waitcnt vmcnt(0)"
                     : "=v"(v) : "v"(slots + tid * FSTRIDE) : "memory");
      if (__all((int)(v >= target))) break;
      __builtin_amdgcn_s_sleep(1);
      if (++cap > (1 << 22)) break;  // fail-visible instead of hanging
    }
  }
  __syncthreads();
}

// ---- W fragment -> registers: lane (lc=col0+(lane&15), q=lane>>4) holds
// W[lc][ks*32 + q*8 .. +8] as bf16 hi/lo short8 per ks. Loaded once. ----------
template <int KK>
__device__ __forceinline__ void loadWfrag(const float* W, int col0, int lane,
                                          short8* wh, short8* wl) {
  const int lc = col0 + (lane & 15);
  const int q = lane >> 4;
#pragma unroll
  for (int ks = 0; ks < KK / 32; ++ks) {
    const float* src = W + (size_t)lc * KK + ks * 32 + q * 8;
    float4 a = *(const float4*)src;
    float4 b = *(const float4*)(src + 4);
    uint4 h = make_uint4(pk(a.x, a.y), pk(a.z, a.w), pk(b.x, b.y), pk(b.z, b.w));
    uint4 l = make_uint4(pk(a.x - hif(a.x), a.y - hif(a.y)),
                         pk(a.z - hif(a.z), a.w - hif(a.w)),
                         pk(b.x - hif(b.x), b.y - hif(b.y)),
                         pk(b.z - hif(b.z), b.w - hif(b.w)));
    wh[ks] = __builtin_bit_cast(short8, h);
    wl[ks] = __builtin_bit_cast(short8, l);
  }
}

// ---- A staging: bf16 hi/lo state planes ([16][512] u16) -> LDS --------------
// 512 threads x 2 chunks x 16B per plane = 16KB per plane.
__device__ __forceinline__ void compute_offs(int tid, int* off, int* lof) {
#pragma unroll
  for (int it = 0; it < 2; ++it) {
    int s = tid + it * NT, rr = s >> 6, ks = s & 63;   // 64 x 16B chunks per row
    off[it] = rr * 1024 + ks * 16;
    lof[it] = off[it] ^ ((rr & 7) << 4);
  }
}
__device__ __forceinline__ void stage4(int tid, const u16* Ph, const u16* Pl,
                                       char* AH, char* AL) {
  int off[2], lof[2];
  compute_offs(tid, off, lof);
  const char* gh = (const char*)Ph;
  const char* gl = (const char*)Pl;
  float4 o0, o1, o2, o3;
  asm volatile(
      "global_load_dwordx4 %0, %4, off sc0 sc1\n\t"
      "global_load_dwordx4 %1, %5, off sc0 sc1\n\t"
      "global_load_dwordx4 %2, %6, off sc0 sc1\n\t"
      "global_load_dwordx4 %3, %7, off sc0 sc1\n\t"
      "s_waitcnt vmcnt(0)"
      : "=&v"(o0), "=&v"(o1), "=&v"(o2), "=&v"(o3)
      : "v"(gh + off[0]), "v"(gh + off[1]), "v"(gl + off[0]), "v"(gl + off[1])
      : "memory");
  *(float4*)(AH + lof[0]) = o0; *(float4*)(AH + lof[1]) = o1;
  *(float4*)(AL + lof[0]) = o2; *(float4*)(AL + lof[1]) = o3;
}
__device__ __forceinline__ void stage8i(int tid, const u16* Ph, const u16* Pl,
                                        char* AH, char* AL,
                                        const float* q0, const float* q1,
                                        const float* q2, const float* q3,
                                        float& i0, float& i1, float& i2, float& i3) {
  int off[2], lof[2];
  compute_offs(tid, off, lof);
  const char* gh = (const char*)Ph;
  const char* gl = (const char*)Pl;
  float4 o0, o1, o2, o3;
  asm volatile(
      "global_load_dword %4, %12, off sc0 sc1\n\t"
      "global_load_dword %5, %13, off sc0 sc1\n\t"
      "global_load_dword %6, %14, off sc0 sc1\n\t"
      "global_load_dword %7, %15, off sc0 sc1\n\t"
      "global_load_dwordx4 %0, %8, off sc0 sc1\n\t"
      "global_load_dwordx4 %1, %9, off sc0 sc1\n\t"
      "global_load_dwordx4 %2, %10, off sc0 sc1\n\t"
      "global_load_dwordx4 %3, %11, off sc0 sc1\n\t"
      "s_waitcnt vmcnt(0)"
      : "=&v"(o0), "=&v"(o1), "=&v"(o2), "=&v"(o3),
        "=&v"(i0), "=&v"(i1), "=&v"(i2), "=&v"(i3)
      : "v"(gh + off[0]), "v"(gh + off[1]), "v"(gl + off[0]), "v"(gl + off[1]),
        "v"(q0), "v"(q1), "v"(q2), "v"(q3)
      : "memory");
  *(float4*)(AH + lof[0]) = o0; *(float4*)(AH + lof[1]) = o1;
  *(float4*)(AL + lof[0]) = o2; *(float4*)(AL + lof[1]) = o3;
}

// ---- bf16x3 MFMA loop: A from LDS, W from registers -------------------------
template <int KK>
__device__ __forceinline__ f32x4 mm_frag_reg(const char* AH, const char* AL,
                                             const short8* wh, const short8* wl,
                                             int lane) {
  constexpr int ROWB = KK * 2;
  const int rr = lane & 15;
  const int kq = (lane >> 4) * 16;
  const int swa = (rr & 7) << 4;
  f32x4 a0 = {0.f, 0.f, 0.f, 0.f}, a1 = {0.f, 0.f, 0.f, 0.f};
#pragma unroll
  for (int ks = 0; ks < KK / 32; ++ks) {
    int ka = rr * ROWB + ks * 64 + kq;
    short8 ah = *(const short8*)(AH + (ka ^ swa));
    short8 al = *(const short8*)(AL + (ka ^ swa));
    a0 = MFMA_B16(ah, wh[ks], a0);
    a1 = MFMA_B16(ah, wl[ks], a1);
    a1 = MFMA_B16(al, wh[ks], a1);
  }
  return a0 + a1;
}

// ---- per-role phase loops (each WG owns 128 cols = 8 waves x 16) ------------
// role h (h0: dt=1, h1: dt=3): h[t] = tanh(im[t] + h[t-1] @ W^T)
__device__ __forceinline__ void run_h(
    int tid, int lane, int w, unsigned* slots, int r, int dt,
    u16* hh, u16* hl, const float* imb, float* hn2base,
    const float* Wsrc, int tn, char* AH, char* AL) {
  short8 wh[16], wl[16];
  loadWfrag<512>(Wsrc, tn * 128 + w * 16, lane, wh, wl);
  gbar(slots, r, 1, tid);
  const int lc15 = lane & 15, r0 = (lane >> 4) * 4;
  const int gcol = tn * 128 + w * 16 + lc15;
  for (int p = 0; p <= S + 3; ++p) {
    int t = p - dt;
    if (t >= 0 && t < S) {
      const u16* Ph = hh + ((t - 1) & 1) * 8192;
      const u16* Pl = hl + ((t - 1) & 1) * 8192;
      const float* iq = imb + (t & 1) * 8192 + (size_t)r0 * H + gcol;
      float i0, i1, i2, i3;
      stage8i(tid, Ph, Pl, AH, AL, iq, iq + H, iq + 2 * H, iq + 3 * H, i0, i1, i2, i3);
      __syncthreads();
      f32x4 s = mm_frag_reg<512>(AH, AL, wh, wl, lane);
      u16* Dh = hh + (t & 1) * 8192;
      u16* Dl = hl + (t & 1) * 8192;
      float iv[4] = {i0, i1, i2, i3};
      bool last = (t == S - 1);
#pragma unroll
      for (int j = 0; j < 4; ++j) {
        float v = ftanh(s[j] + iv[j]);
        unsigned ub = __builtin_bit_cast(unsigned, v);
        float lov = v - __builtin_bit_cast(float, ub & 0xFFFF0000u);
        stg_sys_u16(Dh + (size_t)(r0 + j) * H + gcol, ub >> 16);
        stg_sys_u16(Dl + (size_t)(r0 + j) * H + gcol,
                    __builtin_bit_cast(unsigned, lov) >> 16);
        if (last) hn2base[(size_t)(r0 + j) * H + gcol] = v;
      }
    }
    gbar(slots, r, 2 + p, tid);
  }
}

// role G: G[t] = b_ih1 + b_hh1 + h0[t] @ W_ih1^T  (fp32 out)
__device__ __forceinline__ void run_g(
    int tid, int lane, int w, unsigned* slots, int r,
    const u16* h0h, const u16* h0l, float* Gg,
    const float* b1, const float* b2,
    const float* Wsrc, int tn, char* AH, char* AL) {
  short8 wh[16], wl[16];
  loadWfrag<512>(Wsrc, tn * 128 + w * 16, lane, wh, wl);
  gbar(slots, r, 1, tid);
  const int lc15 = lane & 15, r0 = (lane >> 4) * 4;
  const int gcol = tn * 128 + w * 16 + lc15;
  const float bsum = b1[gcol] + b2[gcol];
  for (int p = 0; p <= S + 3; ++p) {
    int t = p - 2;
    if (t >= 0 && t < S) {
      stage4(tid, h0h + (t & 1) * 8192, h0l + (t & 1) * 8192, AH, AL);
      __syncthreads();
      f32x4 s = mm_frag_reg<512>(AH, AL, wh, wl, lane);
      float* D = Gg + (t & 1) * 8192;
#pragma unroll
      for (int j = 0; j < 4; ++j)
        stg_sys_f32(D + (size_t)(r0 + j) * H + gcol, s[j] + bsum);
    }
    gbar(slots, r, 2 + p, tid);
  }
}

// role Ain: Ain[t] = b_ih0 + b_hh0 + emb[x[:,t]] @ W_ih0^T  (256 cols per WG)
__device__ __forceinline__ void run_ain(
    int tid, int lane, int w, unsigned* slots, int r,
    const int* x, const float* emb, float* Ain,
    const float* b1, const float* b2,
    const float* Wsrc, int a, int gb0, char* AH, char* AL) {
  short8 whA[8], wlA[8], whB[8], wlB[8];
  const int col0 = a * 256 + w * 32;
  loadWfrag<256>(Wsrc, col0, lane, whA, wlA);
  loadWfrag<256>(Wsrc, col0 + 16, lane, whB, wlB);
  gbar(slots, r, 1, tid);
  const int lc15 = lane & 15, r0 = (lane >> 4) * 4;
  const int gcolA = col0 + lc15, gcolB = gcolA + 16;
  const float bsA = b1[gcolA] + b2[gcolA], bsB = b1[gcolB] + b2[gcolB];
  const int rr = tid >> 4, q = tid & 15;   // first 256 threads stage
  for (int p = 0; p <= S + 3; ++p) {
    int t = p;
    if (t < S) {
      if (tid < 256) {
        int idx = x[(size_t)(gb0 + rr) * S + t];
        const float4* src = (const float4*)(emb + (size_t)idx * E + q * 16);
        float4 v0 = src[0], v1 = src[1], v2 = src[2], v3 = src[3];
        uint4 h0v, h1v, l0v, l1v;
        cvt16(v0, v1, v2, v3, h0v, h1v, l0v, l1v);
        int bb = rr * 512 + q * 32, sw = (rr & 7) << 4;
        *(uint4*)(AH + ((bb) ^ sw)) = h0v;
        *(uint4*)(AH + ((bb + 16) ^ sw)) = h1v;
        *(uint4*)(AL + ((bb) ^ sw)) = l0v;
        *(uint4*)(AL + ((bb + 16) ^ sw)) = l1v;
      }
      __syncthreads();
      f32x4 sA = mm_frag_reg<256>(AH, AL, whA, wlA, lane);
      f32x4 sB = mm_frag_reg<256>(AH, AL, whB, wlB, lane);
      float* D = Ain + (t & 1) * 8192;
#pragma unroll
      for (int j = 0; j < 4; ++j) {
        stg_sys_f32(D + (size_t)(r0 + j) * H + gcolA, sA[j] + bsA);
        stg_sys_f32(D + (size_t)(r0 + j) * H + gcolB, sB[j] + bsB);
      }
    }
    gbar(slots, r, 2 + p, tid);
  }
}

// role logits: out[t] = b_out + h1[t] @ W_out^T (one WG, 8 waves x 16 = 128 V)
__device__ __forceinline__ void run_out(
    int tid, int lane, int w, unsigned* slots, int r,
    const u16* h1h, const u16* h1l, float* out, const float* b_out,
    const float* Wsrc, int gb0, char* AH, char* AL) {
  short8 wh[16], wl[16];
  loadWfrag<512>(Wsrc, w * 16, lane, wh, wl);
  gbar(slots, r, 1, tid);
  const int lc15 = lane & 15, r0 = (lane >> 4) * 4;
  const int gcol = w * 16 + lc15;
  const float bv = b_out[gcol];
  for (int p = 0; p <= S + 3; ++p) {
    int t = p - 4;
    if (t >= 0 && t < S) {
      stage4(tid, h1h + (t & 1) * 8192, h1l + (t & 1) * 8192, AH, AL);
      __syncthreads();
      f32x4 s = mm_frag_reg<512>(AH, AL, wh, wl, lane);
#pragma unroll
      for (int j = 0; j < 4; ++j)
        out[((size_t)(gb0 + r0 + j) * S + t) * V + gcol] = s[j] + bv;
    }
    gbar(slots, r, 2 + p, tid);
  }
}

// Grouping by blockIdx (placement-independent correctness, G16).
// Roles within a 15-WG group (16 batch rows, 512-thread WGs):
//  r [0,4): h0 t=p-1 | r [4,8): G t=p-2 | r [8,12): h1 t=p-3
//  r [12,14): Ain t=p (256 cols) | r 14: logits t=p-4
__global__ void __launch_bounds__(NT, 1) rnn_pers(
    const int* __restrict__ x, const float* __restrict__ emb,
    const float* __restrict__ W_ih0, const float* __restrict__ b_ih0,
    const float* __restrict__ W_hh0, const float* __restrict__ b_hh0,
    const float* __restrict__ W_ih1, const float* __restrict__ b_ih1,
    const float* __restrict__ W_hh1, const float* __restrict__ b_hh1,
    const float* __restrict__ W_out, const float* __restrict__ b_out,
    float* __restrict__ out, float* __restrict__ ws)
{
  extern __shared__ char lds[];
  char* AH = lds;
  char* AL = lds + 16384;

  const int tid = threadIdx.x;
  const int g = blockIdx.x >> 4;
  const int r = blockIdx.x & 15;
  if (r >= WPG) return;

  unsigned* slots = (unsigned*)ws + (size_t)g * (WPG * FSTRIDE + 16);
  float* base = ws + 2048 + (size_t)g * 65536;
  float* Ain = base;                 // fp32 [2][16][512]
  float* Gg  = base + 16384;         // fp32 [2][16][512]
  u16* h0h = (u16*)(base + 32768);   // bf16-hi/lo [2][16][512] x4 planes
  u16* h0l = h0h + 16384;
  u16* h1h = h0h + 32768;
  u16* h1l = h0h + 49152;
  const int gb0 = g * GB;

  // Zero h-state planes (both slots, 4 planes = 32768 u32), system scope.
  {
    unsigned* zp = (unsigned*)h0h;
    for (int i = r * NT + tid; i < 32768; i += WPG * NT) stg_sys_u32(zp + i, 0u);
  }

  const int lane = tid & 63, w = tid >> 6;
  float* hn = out + (size_t)B * S * V;

  if (r < 4)
    run_h(tid, lane, w, slots, r, 1, h0h, h0l, Ain,
          hn + (size_t)gb0 * H, W_hh0, r, AH, AL);
  else if (r < 8)
    run_g(tid, lane, w, slots, r, h0h, h0l, Gg, b_ih1, b_hh1,
          W_ih1, r - 4, AH, AL);
  else if (r < 12)
    run_h(tid, lane, w, slots, r, 3, h1h, h1l, Gg,
          hn + (size_t)B * H + (size_t)gb0 * H, W_hh1, r - 8, AH, AL);
  else if (r < 14)
    run_ain(tid, lane, w, slots, r, x, emb, Ain, b_ih0, b_hh0,
            W_ih0, r - 12, gb0, AH, AL);
  else
    run_out(tid, lane, w, slots, r, h1h, h1l, out, b_out,
            W_out, gb0, AH, AL);
}

extern "C" void kernel_launch(void* const* d_in, const int* in_sizes, int n_in,
                              void* d_out, int out_size, void* d_ws, size_t ws_size,
                              hipStream_t stream) {
  const int*   x     = (const int*)d_in[0];
  const float* emb   = (const float*)d_in[1];
  const float* W_ih0 = (const float*)d_in[2];
  const float* b_ih0 = (const float*)d_in[3];
  const float* W_hh0 = (const float*)d_in[4];
  const float* b_hh0 = (const float*)d_in[5];
  const float* W_ih1 = (const float*)d_in[6];
  const float* b_ih1 = (const float*)d_in[7];
  const float* W_hh1 = (const float*)d_in[8];
  const float* b_hh1 = (const float*)d_in[9];
  const float* W_out = (const float*)d_in[10];
  const float* b_out = (const float*)d_in[11];
  float* out = (float*)d_out;
  float* ws  = (float*)d_ws;

  hipFuncSetAttribute((const void*)rnn_pers,
                      hipFuncAttributeMaxDynamicSharedMemorySize, (int)LDS_BYTES);
  // Zero the (cacheline-spread) barrier flag region: 8 groups x 256 u32 = 8KB.
  hipMemsetAsync(ws, 0, 8192, stream);

  void* args[] = { &x, &emb, &W_ih0, &b_ih0, &W_hh0, &b_hh0, &W_ih1, &b_ih1,
                   &W_hh1, &b_hh1, &W_out, &b_out, &out, &ws };
  hipLaunchCooperativeKernel((const void*)rnn_pers, dim3(NWG), dim3(NT),
                             args, LDS_BYTES, stream);
}